// Round 12
// baseline (374.945 us; speedup 1.0000x reference)
//
#include <hip/hip_runtime.h>
#include <stdint.h>

#define NN 100000
#define NE 1600000
#define NG 64
#define DIN 128
#define HID 256
#define NATTR 8
#define NBK 391      // dst buckets of 256 nodes
#define CAP 6144     // bucket capacity (max ~4400)
#define PCH 4096     // edges per partition chunk
#define BWW 25000    // Wbt build window
#define CB 12756     // cast/tw blocks: (NN*DIN/4 + 65536)/256

typedef unsigned short u16;
typedef __attribute__((ext_vector_type(8))) short s16x8;
typedef __attribute__((ext_vector_type(4))) float f32x4;

__device__ __forceinline__ int imaxi(int a, int b) { return a > b ? a : b; }
__device__ __forceinline__ u16 f2bf(float f) {
    unsigned u = __float_as_uint(f);
    return (u16)((u + 0x7fffu + ((u >> 16) & 1u)) >> 16);  // RNE
}
__device__ __forceinline__ void gload16(const void* g, void* l) {
    __builtin_amdgcn_global_load_lds((const __attribute__((address_space(1))) void*)g,
                                     (__attribute__((address_space(3))) void*)l, 16, 0, 0);
}

// ---------------- prep: cast x, transpose W1, zero P8/cursor, goff/gcnt ----------------

__global__ void k_prep(const float4* __restrict__ x4, ushort4* __restrict__ xb4,
                       const float* __restrict__ W1l, const float* __restrict__ W1r,
                       u16* __restrict__ W1lt, u16* __restrict__ W1rt,
                       float4* __restrict__ P84, const int* __restrict__ batch,
                       int* __restrict__ goff, int* __restrict__ gcnt,
                       int* __restrict__ cursor) {
    int b = blockIdx.x, t = threadIdx.x;
    if (b < CB) {
        int i = b * 256 + t;
        const int NX4 = NN * DIN / 4;  // 3,200,000
        if (i < NX4) {
            float4 v = x4[i];
            ushort4 o;
            o.x = f2bf(v.x); o.y = f2bf(v.y); o.z = f2bf(v.z); o.w = f2bf(v.w);
            xb4[i] = o;
        } else {
            int j = i - NX4;
            if (j < 32768) {
                int n = j >> 7, k = j & 127;
                W1lt[j] = f2bf(W1l[k * HID + n]);
            } else if (j < 65536) {
                int jj = j - 32768;
                int n = jj >> 7, k = jj & 127;
                W1rt[jj] = f2bf(W1r[k * HID + n]);
            }
        }
    } else if (b < CB + 256) {
        int i = (b - CB) * 256 + t;  // exactly 65536 = 8*128*HID/4
        P84[i] = make_float4(0.f, 0.f, 0.f, 0.f);
    } else {
        for (int i = t; i < NBK; i += 256) cursor[i] = 0;
        int g = t;
        if (g <= NG) {
            int lo = 0, hi = NN;
            while (lo < hi) {
                int mid = (lo + hi) >> 1;
                if (batch[mid] < g) lo = mid + 1; else hi = mid;
            }
            goff[g] = lo;
        }
        __syncthreads();
        if (g < NG) gcnt[g] = goff[g + 1] - goff[g];
    }
}

// ---------------- pass 1: radix partition, packed (dlocal<<24)|src, 512 thr ----------------

__global__ __launch_bounds__(512) void k_part(const int* __restrict__ ei,
                                              int* __restrict__ cursor,
                                              unsigned* __restrict__ pairs) {
    __shared__ unsigned spk[PCH];       // 16 KB
    __shared__ unsigned short sbk[PCH]; // 8 KB
    __shared__ int hist[NBK], gb[NBK];
    __shared__ int sc[512];
    int t = threadIdx.x;
    int c0 = blockIdx.x * PCH;
    int n = NE - c0; if (n > PCH) n = PCH;
    for (int i = t; i < NBK; i += 512) hist[i] = 0;
    __syncthreads();
    unsigned mypk[8]; unsigned short mybk[8]; int myoff[8];
#pragma unroll
    for (int j = 0; j < 8; j++) {
        int i = t + j * 512;
        myoff[j] = -1;
        if (i < n) {
            int e = c0 + i;
            unsigned d = (unsigned)__builtin_nontemporal_load(&ei[NE + e]);
            unsigned s = (unsigned)__builtin_nontemporal_load(&ei[e]);
            unsigned bk = d >> 8;
            mypk[j] = ((d & 255u) << 24) | s;
            mybk[j] = (unsigned short)bk;
            myoff[j] = atomicAdd(&hist[bk], 1);
        }
    }
    __syncthreads();
    sc[t] = (t < NBK) ? hist[t] : 0;
    __syncthreads();
    for (int off = 1; off < 512; off <<= 1) {
        int v = (t >= off) ? sc[t - off] : 0;
        __syncthreads();
        sc[t] += v;
        __syncthreads();
    }
    if (t < NBK && hist[t] > 0) gb[t] = atomicAdd(&cursor[t], hist[t]);
    __syncthreads();
#pragma unroll
    for (int j = 0; j < 8; j++) {
        if (myoff[j] >= 0) {
            int bk = mybk[j];
            int pos = sc[bk] - hist[bk] + myoff[j];
            spk[pos] = mypk[j];
            sbk[pos] = (unsigned short)bk;
        }
    }
    __syncthreads();
    for (int i = t; i < n; i += 512) {
        int bk = sbk[i];
        int local = gb[bk] + (i - (sc[bk] - hist[bk]));
        pairs[(size_t)bk * CAP + local] = spk[i];
    }
}

// ---------------- pass 2: per-bucket CSR (self-computed base, LDS only, 512 thr) ----------------

__global__ __launch_bounds__(512) void k_csr(const unsigned* __restrict__ pairs,
                                             const int* __restrict__ cursor,
                                             int* __restrict__ rowptr,
                                             unsigned* __restrict__ col) {
    __shared__ unsigned colL[CAP];   // 24 KB
    __shared__ int csc[512];
    __shared__ int cnt[256], cur[256], sc[256];
    int b = blockIdx.x, t = threadIdx.x;
    csc[t] = (t < NBK) ? cursor[t] : 0;
    __syncthreads();
    for (int off = 1; off < 512; off <<= 1) {
        int v = (t >= off) ? csc[t - off] : 0;
        __syncthreads();
        csc[t] += v;
        __syncthreads();
    }
    int obase = (b == 0) ? 0 : csc[b - 1];
    int ecnt = cursor[b];
    const unsigned* pp = pairs + (size_t)b * CAP;
    if (t < 256) cnt[t] = 0;
    __syncthreads();
    for (int i = t; i < ecnt; i += 512)
        atomicAdd(&cnt[pp[i] >> 24], 1);
    __syncthreads();
    if (t < 256) sc[t] = cnt[t];
    __syncthreads();
    for (int off = 1; off < 256; off <<= 1) {
        int v = 0;
        if (t < 256 && t >= off) v = sc[t - off];
        __syncthreads();
        if (t < 256) sc[t] += v;
        __syncthreads();
    }
    if (t < 256) {
        int lr = sc[t] - cnt[t];
        cur[t] = lr;
        int node = (b << 8) + t;
        if (node < NN) rowptr[node] = obase + lr;
        if (b == NBK - 1 && t == 0) rowptr[NN] = obase + ecnt;
    }
    __syncthreads();
    for (int i = t; i < ecnt; i += 512) {
        unsigned p = pp[i];
        int dl = p >> 24;
        int pos = atomicAdd(&cur[dl], 1);
        int dd = cnt[dl]; if (dd > 32767) dd = 32767;
        colL[pos] = ((unsigned)dd << 17) | (p & 0xFFFFFFu);
    }
    __syncthreads();
    for (int i = t; i < ecnt; i += 512)
        col[obase + i] = colL[i];
}

// ---------------- layer-1 mean aggregation (quarter-wave, uint4 rows) ----------------

__global__ void k_agg(const uint4* __restrict__ xb4, uint4* __restrict__ agg4,
                      const int* __restrict__ rowptr, const unsigned* __restrict__ col) {
    int node = blockIdx.x * 4 + (threadIdx.x >> 6);
    int lane = threadIdx.x & 63;
    if (node >= NN) return;
    int qtr = lane >> 4, li = lane & 15;
    int s = rowptr[node], e = rowptr[node + 1];
    float a0 = 0, a1 = 0, a2 = 0, a3 = 0, a4 = 0, a5 = 0, a6 = 0, a7 = 0;
#define ACC8(V) do { \
        a0 += __uint_as_float((V).x << 16); a1 += __uint_as_float((V).x & 0xffff0000u); \
        a2 += __uint_as_float((V).y << 16); a3 += __uint_as_float((V).y & 0xffff0000u); \
        a4 += __uint_as_float((V).z << 16); a5 += __uint_as_float((V).z & 0xffff0000u); \
        a6 += __uint_as_float((V).w << 16); a7 += __uint_as_float((V).w & 0xffff0000u); } while (0)
    int i = s;
    for (; i + 16 <= e; i += 16) {
        unsigned c0 = col[i + qtr] & 0x1FFFFu;
        unsigned c1 = col[i + 4 + qtr] & 0x1FFFFu;
        unsigned c2 = col[i + 8 + qtr] & 0x1FFFFu;
        unsigned c3 = col[i + 12 + qtr] & 0x1FFFFu;
        uint4 w0 = xb4[(size_t)c0 * 16 + li];
        uint4 w1 = xb4[(size_t)c1 * 16 + li];
        uint4 w2 = xb4[(size_t)c2 * 16 + li];
        uint4 w3 = xb4[(size_t)c3 * 16 + li];
        ACC8(w0); ACC8(w1); ACC8(w2); ACC8(w3);
    }
    for (; i + 4 <= e; i += 4) {
        unsigned c = col[i + qtr] & 0x1FFFFu;
        uint4 wv = xb4[(size_t)c * 16 + li];
        ACC8(wv);
    }
    if (i + qtr < e) {
        unsigned c = col[i + qtr] & 0x1FFFFu;
        uint4 wv = xb4[(size_t)c * 16 + li];
        ACC8(wv);
    }
#undef ACC8
    a0 += __shfl_xor(a0, 16); a1 += __shfl_xor(a1, 16);
    a2 += __shfl_xor(a2, 16); a3 += __shfl_xor(a3, 16);
    a4 += __shfl_xor(a4, 16); a5 += __shfl_xor(a5, 16);
    a6 += __shfl_xor(a6, 16); a7 += __shfl_xor(a7, 16);
    a0 += __shfl_xor(a0, 32); a1 += __shfl_xor(a1, 32);
    a2 += __shfl_xor(a2, 32); a3 += __shfl_xor(a3, 32);
    a4 += __shfl_xor(a4, 32); a5 += __shfl_xor(a5, 32);
    a6 += __shfl_xor(a6, 32); a7 += __shfl_xor(a7, 32);
    if (qtr == 0) {
        float inv = 1.f / (float)imaxi(e - s, 1);
        uint4 o;
        o.x = (((unsigned)f2bf(a1 * inv)) << 16) | (unsigned)f2bf(a0 * inv);
        o.y = (((unsigned)f2bf(a3 * inv)) << 16) | (unsigned)f2bf(a2 * inv);
        o.z = (((unsigned)f2bf(a5 * inv)) << 16) | (unsigned)f2bf(a4 * inv);
        o.w = (((unsigned)f2bf(a7 * inv)) << 16) | (unsigned)f2bf(a6 * inv);
        agg4[(size_t)node * 16 + li] = o;
    }
}

// ---------------- MFMA GEMM1: h1t = relu(agg1@W1l + x@W1r + b1)^T ----------------

__global__ __launch_bounds__(512) void k_gemm1(
    const u16* __restrict__ agg1, const u16* __restrict__ xb,
    const u16* __restrict__ W1lt, const u16* __restrict__ W1rt,
    const float* __restrict__ b1, u16* __restrict__ h1t) {
    __shared__ u16 As[128][32];   // 8 KB
    __shared__ u16 Bs[256][32];   // 16 KB
    int t = threadIdx.x;
    int m0 = blockIdx.x * 128;
    int wave = t >> 6, lane = t & 63;
    int wm = wave & 1, wn = wave >> 1;
    int lm = lane & 15, quad = lane >> 4;
    int ar = t >> 2, aq = t & 3;
    f32x4 acc[4][4] = {};
    const u16* Ap = agg1;
    const u16* Bp = W1lt;
#pragma unroll
    for (int ph = 0; ph < 2; ph++) {
        for (int k0 = 0; k0 < DIN; k0 += 32) {
            gload16(Ap + (size_t)(m0 + ar) * DIN + k0 + aq * 8, &As[wave * 16][0]);
#pragma unroll
            for (int i = 0; i < 2; i++) {
                int r = (t + i * 512) >> 2;
                gload16(Bp + (size_t)r * DIN + k0 + aq * 8, &Bs[wave * 16 + i * 128][0]);
            }
            __syncthreads();
            s16x8 af[4], bfr[4];
#pragma unroll
            for (int i = 0; i < 4; i++) {
                af[i]  = *(const s16x8*)&As[wm * 64 + i * 16 + lm][quad * 8];
                bfr[i] = *(const s16x8*)&Bs[wn * 64 + i * 16 + lm][quad * 8];
            }
#pragma unroll
            for (int mi = 0; mi < 4; mi++)
#pragma unroll
                for (int ni = 0; ni < 4; ni++)
                    acc[mi][ni] = __builtin_amdgcn_mfma_f32_16x16x32_bf16(
                        af[mi], bfr[ni], acc[mi][ni], 0, 0, 0);
            __syncthreads();
        }
        Ap = xb; Bp = W1rt;
    }
#pragma unroll
    for (int ni = 0; ni < 4; ni++) {
        int colf = wn * 64 + ni * 16 + lm;  // feature 0..255
        float bias = b1[colf];
#pragma unroll
        for (int mi = 0; mi < 4; mi++) {
            int row = m0 + wm * 64 + mi * 16 + quad * 4;  // node
            if (row < NN) {
                ushort4 o;
                o.x = f2bf(fmaxf(acc[mi][ni][0] + bias, 0.f));
                o.y = f2bf(fmaxf(acc[mi][ni][1] + bias, 0.f));
                o.z = f2bf(fmaxf(acc[mi][ni][2] + bias, 0.f));
                o.w = f2bf(fmaxf(acc[mi][ni][3] + bias, 0.f));
                *(ushort4*)(h1t + (size_t)colf * NN + row) = o;
            }
        }
    }
}

// ---------------- atomic-free Wbt build (bf16, dense writes) ----------------

__global__ __launch_bounds__(256) void k_bw(
    const int* __restrict__ rowptr, const unsigned* __restrict__ col,
    const int* __restrict__ goff, u16* __restrict__ Wbt) {
    int b = blockIdx.x, t = threadIdx.x;
    if (b < 256) {
        __shared__ float bins[BWW];
        int g = b >> 2, w = b & 3;
        int lo = w * BWW;
        for (int i = t; i < BWW; i += 256) bins[i] = 0.f;
        __syncthreads();
        int ebeg = rowptr[goff[g]], eend = rowptr[goff[g + 1]];
        for (int i = ebeg + t; i < eend; i += 256) {
            unsigned c = col[i];
            unsigned sl = (c & 0x1FFFFu) - lo;
            if (sl < (unsigned)BWW) atomicAdd(&bins[sl], 1.0f / (float)(c >> 17));
        }
        __syncthreads();
        u16* out = Wbt + (size_t)g * NN + lo;
        for (int k = t; k < BWW / 4; k += 256) {
            ushort4 o;
            o.x = f2bf(bins[4 * k + 0]); o.y = f2bf(bins[4 * k + 1]);
            o.z = f2bf(bins[4 * k + 2]); o.w = f2bf(bins[4 * k + 3]);
            *(ushort4*)(out + 4 * k) = o;
        }
    } else {
        int g = b - 256;
        int a = goff[g], bnd = goff[g + 1];
        u16* out = Wbt + (size_t)(NG + g) * NN;
        for (int k = t; k < NN / 4; k += 256) {
            int c0 = 4 * k;
            ushort4 o;
            o.x = (c0 + 0 >= a && c0 + 0 < bnd) ? 0x3F80 : 0;
            o.y = (c0 + 1 >= a && c0 + 1 < bnd) ? 0x3F80 : 0;
            o.z = (c0 + 2 >= a && c0 + 2 < bnd) ? 0x3F80 : 0;
            o.w = (c0 + 3 >= a && c0 + 3 < bnd) ? 0x3F80 : 0;
            *(ushort4*)(out + c0) = o;
        }
    }
}

// ---------------- pool GEMM: P = Wbt @ h1t^T (128x256, split-K 256) ----------------

#define KCHUNK 256

__global__ __launch_bounds__(512) void k_poolg(
    const u16* __restrict__ Wbt, const u16* __restrict__ h1t, float* __restrict__ P8) {
    __shared__ u16 As[128][32];
    __shared__ u16 Bs[256][32];
    int t = threadIdx.x;
    int kbase = blockIdx.x * KCHUNK;
    int krem = NN - kbase;
    int ksteps = (krem < KCHUNK ? krem : KCHUNK) >> 5;
    int wave = t >> 6, lane = t & 63;
    int wm = wave & 1, wn = wave >> 1;
    int lm = lane & 15, quad = lane >> 4;
    int ar = t >> 2, aq = t & 3;
    float* P = P8 + (size_t)(blockIdx.x & 7) * 128 * HID;
    f32x4 acc[4][4] = {};
    for (int ks = 0; ks < ksteps; ks++) {
        int k0 = kbase + ks * 32;
        gload16(Wbt + (size_t)ar * NN + k0 + aq * 8, &As[wave * 16][0]);
#pragma unroll
        for (int i = 0; i < 2; i++) {
            int r = (t + i * 512) >> 2;
            gload16(h1t + (size_t)r * NN + k0 + aq * 8, &Bs[wave * 16 + i * 128][0]);
        }
        __syncthreads();
        s16x8 af[4], bfr[4];
#pragma unroll
        for (int i = 0; i < 4; i++) {
            af[i]  = *(const s16x8*)&As[wm * 64 + i * 16 + lm][quad * 8];
            bfr[i] = *(const s16x8*)&Bs[wn * 64 + i * 16 + lm][quad * 8];
        }
#pragma unroll
        for (int mi = 0; mi < 4; mi++)
#pragma unroll
            for (int ni = 0; ni < 4; ni++)
                acc[mi][ni] = __builtin_amdgcn_mfma_f32_16x16x32_bf16(
                    af[mi], bfr[ni], acc[mi][ni], 0, 0, 0);
        __syncthreads();
    }
#pragma unroll
    for (int mi = 0; mi < 4; mi++)
#pragma unroll
        for (int ni = 0; ni < 4; ni++) {
            int gcol = wm * 64 + mi * 16 + quad * 4;
            int feat = wn * 64 + ni * 16 + lm;
#pragma unroll
            for (int r = 0; r < 4; r++)
                atomicAdd(&P[(gcol + r) * HID + feat], acc[mi][ni][r]);
        }
}

// ---------------- head ----------------

__global__ void k_head(const float* __restrict__ P8, const int* __restrict__ gcnt,
                       const float* __restrict__ gattr,
                       const float* __restrict__ W2l, const float* __restrict__ b2,
                       const float* __restrict__ W2r,
                       const float* __restrict__ Wf1, const float* __restrict__ bf1,
                       const float* __restrict__ Wf2, const float* __restrict__ bf2v,
                       float* __restrict__ out) {
    __shared__ float pa[HID], ph[HID], gv[HID + NATTR];
    __shared__ float red[256];
    int g = blockIdx.x, t = threadIdx.x;
    float sa = 0.f, sh = 0.f;
#pragma unroll
    for (int c = 0; c < 8; c++) {
        sa += P8[(size_t)c * 128 * HID + g * HID + t];
        sh += P8[(size_t)c * 128 * HID + (NG + g) * HID + t];
    }
    pa[t] = sa; ph[t] = sh;
    __syncthreads();
    float s = 0.f;
    for (int k = 0; k < HID; k++)
        s += pa[k] * W2l[k * HID + t] + ph[k] * W2r[k * HID + t];
    float invc = 1.f / (float)imaxi(gcnt[g], 1);
    gv[t] = s * invc + b2[t];
    if (t < NATTR) gv[HID + t] = gattr[g * NATTR + t];
    __syncthreads();
    float h = bf1[t];
    for (int k = 0; k < HID + NATTR; k++) h += gv[k] * Wf1[k * HID + t];
    h = fmaxf(h, 0.f);
    red[t] = h * Wf2[t];
    __syncthreads();
    for (int off = 128; off > 0; off >>= 1) {
        if (t < off) red[t] += red[t + off];
        __syncthreads();
    }
    if (t == 0) out[g] = red[0] + bf2v[0];
}

// ---------------- launch ----------------

extern "C" void kernel_launch(void* const* d_in, const int* in_sizes, int n_in,
                              void* d_out, int out_size, void* d_ws, size_t ws_size,
                              hipStream_t stream) {
    (void)in_sizes; (void)n_in; (void)out_size; (void)ws_size;
    const float* x     = (const float*)d_in[0];
    const int*   ei    = (const int*)d_in[1];
    const int*   batch = (const int*)d_in[2];
    const float* gattr = (const float*)d_in[3];
    const float* W1l   = (const float*)d_in[4];
    const float* b1    = (const float*)d_in[5];
    const float* W1r   = (const float*)d_in[6];
    const float* W2l   = (const float*)d_in[7];
    const float* b2    = (const float*)d_in[8];
    const float* W2r   = (const float*)d_in[9];
    const float* Wf1   = (const float*)d_in[10];
    const float* bf1   = (const float*)d_in[11];
    const float* Wf2   = (const float*)d_in[12];
    const float* bf2v  = (const float*)d_in[13];
    float* out = (float*)d_out;

    uint8_t* w = (uint8_t*)d_ws;
    size_t off = 0;
    auto alloc = [&](size_t bytes) -> void* {
        void* p = w + off;
        off += (bytes + 255) & ~(size_t)255;
        return p;
    };
    u16*      xb     = (u16*)alloc((size_t)NN * DIN * 2);        // 25.6 MB
    u16*      agg1   = (u16*)alloc((size_t)NN * DIN * 2);        // 25.6 MB
    u16*      h1t    = (u16*)alloc((size_t)NN * HID * 2);        // 51.2 MB
    u16*      Wbt    = (u16*)alloc((size_t)128 * NN * 2);        // 25.6 MB
    u16*      W1lt   = (u16*)alloc((size_t)HID * DIN * 2);
    u16*      W1rt   = (u16*)alloc((size_t)HID * DIN * 2);
    unsigned* pairs  = (unsigned*)alloc((size_t)NBK * CAP * 4);  // 9.6 MB
    int*      rowptr = (int*)alloc((size_t)(NN + 1) * 4);
    unsigned* col    = (unsigned*)alloc((size_t)NE * 4);         // 6.4 MB
    int*      cursor = (int*)alloc((NBK + 1) * 4);
    int*      goff   = (int*)alloc((NG + 1) * 4);
    int*      gcnt   = (int*)alloc(NG * 4);
    float*    P8     = (float*)alloc((size_t)8 * 128 * HID * 4); // 1 MB

    k_prep<<<CB + 257, 256, 0, stream>>>((const float4*)x, (ushort4*)xb, W1l, W1r,
                                         W1lt, W1rt, (float4*)P8, batch, goff, gcnt,
                                         cursor);

    k_part<<<(NE + PCH - 1) / PCH, 512, 0, stream>>>(ei, cursor, pairs);
    k_csr<<<NBK, 512, 0, stream>>>(pairs, cursor, rowptr, col);

    k_agg<<<NN / 4, 256, 0, stream>>>((const uint4*)xb, (uint4*)agg1, rowptr, col);
    k_gemm1<<<(NN + 127) / 128, 512, 0, stream>>>(agg1, xb, W1lt, W1rt, b1, h1t);

    k_bw<<<320, 256, 0, stream>>>(rowptr, col, goff, Wbt);
    k_poolg<<<(NN + KCHUNK - 1) / KCHUNK, 512, 0, stream>>>(Wbt, h1t, P8);

    k_head<<<NG, 256, 0, stream>>>(P8, gcnt, gattr, W2l, b2, W2r, Wf1, bf1, Wf2, bf2v, out);
}